// Round 8
// baseline (273.422 us; speedup 1.0000x reference)
//
#include <hip/hip_runtime.h>
#include <math.h>

// Problem constants
#define B_   8
#define N_   2048
#define M_   512
#define C_   256
#define NR_  4
#define J_   8192          // NR_*N_ — contiguous column space per (b, channel)
#define CIN1 512
#define BN_CNT 65536.0f
#define NSLICE 512         // BN partial slices: 8 b * 32 jblk * 2 wn

using f16   = _Float16;
using f16x2 = __attribute__((ext_vector_type(2))) _Float16;
using f16x8 = __attribute__((ext_vector_type(8))) _Float16;
using f32x4 = __attribute__((ext_vector_type(4))) float;

// ---------------------------------------------------------------------------
// 3-NN + inverse-distance weights. 8 sub-lanes/point, shuffle-merge top-3.
// grid (N/32, B), block 256
// ---------------------------------------------------------------------------
#define KNN_INSERT(e, j)                                              \
  do {                                                                \
    if ((e) < d0)      { d2v = d1; i2 = i1; d1 = d0; i1 = i0; d0 = (e); i0 = (j); } \
    else if ((e) < d1) { d2v = d1; i2 = i1; d1 = (e); i1 = (j); }     \
    else if ((e) < d2v){ d2v = (e); i2 = (j); }                       \
  } while (0)

__global__ __launch_bounds__(256) void knn_kernel(
    const float* __restrict__ unknown, const float* __restrict__ known,
    int* __restrict__ idx_out, float* __restrict__ w_out)
{
  __shared__ float4 kp[M_];
  const int b = blockIdx.y;
  const int t = threadIdx.x;
  for (int i = t; i < M_; i += 256) {
    const float kx = known[(b * M_ + i) * 3 + 0];
    const float ky = known[(b * M_ + i) * 3 + 1];
    const float kz = known[(b * M_ + i) * 3 + 2];
    kp[(i & 63) * 8 + (i >> 6)] = make_float4(kx, ky, kz, kx * kx + ky * ky + kz * kz);
  }
  __syncthreads();

  const int p = t >> 3;          // point within block (0..31)
  const int s = t & 7;           // M-chunk (0..7)
  const int n = blockIdx.x * 32 + p;
  const float ux = unknown[(b * N_ + n) * 3 + 0];
  const float uy = unknown[(b * N_ + n) * 3 + 1];
  const float uz = unknown[(b * N_ + n) * 3 + 2];
  const float un2 = ux * ux + uy * uy + uz * uz;

  float d0 = 3.4e38f, d1 = 3.4e38f, d2v = 3.4e38f;
  int i0 = 0, i1 = 0, i2 = 0;
#pragma unroll 8
  for (int it = 0; it < 64; ++it) {
    const float4 k4 = kp[it * 8 + s];
    const int m = s * 64 + it;
    const float d = (un2 + k4.w) - 2.0f * (ux * k4.x + uy * k4.y + uz * k4.z);
    KNN_INSERT(d, m);
  }
#pragma unroll
  for (int off = 1; off < 8; off <<= 1) {
    const float e0 = __shfl_xor(d0, off), e1 = __shfl_xor(d1, off), e2 = __shfl_xor(d2v, off);
    const int   j0 = __shfl_xor(i0, off), j1 = __shfl_xor(i1, off), j2 = __shfl_xor(i2, off);
    KNN_INSERT(e0, j0);
    KNN_INSERT(e1, j1);
    KNN_INSERT(e2, j2);
  }
  if (s == 0) {
    const float r0 = 1.0f / (sqrtf(fmaxf(d0, 0.f)) + 1e-8f);
    const float r1 = 1.0f / (sqrtf(fmaxf(d1, 0.f)) + 1e-8f);
    const float r2 = 1.0f / (sqrtf(fmaxf(d2v, 0.f)) + 1e-8f);
    const float rs = r0 + r1 + r2;
    const int base = (b * N_ + n) * 3;
    idx_out[base + 0] = i0; idx_out[base + 1] = i1; idx_out[base + 2] = i2;
    w_out[base + 0] = r0 / rs; w_out[base + 1] = r1 / rs; w_out[base + 2] = r2 / rs;
  }
}

// ---------------------------------------------------------------------------
// prep: interp (gather) + uf fp32->f16 streaming copy in one heterogeneous grid.
//   blockIdx.y <  64 : interp -> x16  (2 n's x 4 c's per thread)
//   blockIdx.y >= 64 : uf -> uf16 (16 elems/thread; 4*32*32=4096 blocks)
// grid (4, 96, 32), block 256
// ---------------------------------------------------------------------------
__global__ __launch_bounds__(256) void prep_kernel(
    const float* __restrict__ kf, const int* __restrict__ idx,
    const float* __restrict__ wgt, f16* __restrict__ x16,
    const float* __restrict__ uf, f16* __restrict__ uf16)
{
  if (blockIdx.y < 64) {
    const int n0 = (blockIdx.x * 256 + threadIdx.x) * 2;
    const int c0 = blockIdx.y * 4;
    const int b = blockIdx.z >> 2, r = blockIdx.z & 3;
    const int ba = (b * N_ + n0) * 3;
    const int ia0 = idx[ba + 0], ia1 = idx[ba + 1], ia2 = idx[ba + 2];
    const int ib0 = idx[ba + 3], ib1 = idx[ba + 4], ib2 = idx[ba + 5];
    const float wa0 = wgt[ba + 0], wa1 = wgt[ba + 1], wa2 = wgt[ba + 2];
    const float wb0 = wgt[ba + 3], wb1 = wgt[ba + 4], wb2 = wgt[ba + 5];
#pragma unroll
    for (int cc = 0; cc < 4; ++cc) {
      const int c = c0 + cc;
      const float* row = kf + (((size_t)b * C_ + c) * NR_ + r) * M_;
      f16x2 v;
      v[0] = (f16)(wa0 * row[ia0] + wa1 * row[ia1] + wa2 * row[ia2]);
      v[1] = (f16)(wb0 * row[ib0] + wb1 * row[ib1] + wb2 * row[ib2]);
      *(f16x2*)&x16[(((size_t)b * C_ + c) * NR_ + r) * N_ + n0] = v;
    }
  } else {
    // uf copy: 4096 blocks x 256 threads x 16 elems = 16,777,216
    const size_t u = ((size_t)(blockIdx.z * 32 + (blockIdx.y - 64)) * 4 + blockIdx.x) * 256 + threadIdx.x;
    const size_t e = u * 16;
    const float4 a0 = *(const float4*)&uf[e + 0];
    const float4 a1 = *(const float4*)&uf[e + 4];
    const float4 a2 = *(const float4*)&uf[e + 8];
    const float4 a3 = *(const float4*)&uf[e + 12];
    f16x8 v0, v1;
    v0[0] = (f16)a0.x; v0[1] = (f16)a0.y; v0[2] = (f16)a0.z; v0[3] = (f16)a0.w;
    v0[4] = (f16)a1.x; v0[5] = (f16)a1.y; v0[6] = (f16)a1.z; v0[7] = (f16)a1.w;
    v1[0] = (f16)a2.x; v1[1] = (f16)a2.y; v1[2] = (f16)a2.z; v1[3] = (f16)a2.w;
    v1[4] = (f16)a3.x; v1[5] = (f16)a3.y; v1[6] = (f16)a3.z; v1[7] = (f16)a3.w;
    *(f16x8*)&uf16[e + 0] = v0;
    *(f16x8*)&uf16[e + 8] = v1;
  }
}

// ---------------------------------------------------------------------------
// Weight fp32 -> f16 (W1 256x512, W2 256x256). grid 512, block 256
// ---------------------------------------------------------------------------
__global__ __launch_bounds__(256) void cvt_w_kernel(
    const float* __restrict__ W1, const float* __restrict__ W2,
    f16* __restrict__ w1h, f16* __restrict__ w2h)
{
  const int i = blockIdx.x * 256 + threadIdx.x;
  if (i < 256 * 512) w1h[i] = (f16)W1[i];
  if (i < 256 * 256) w2h[i] = (f16)W2[i];
}

// ---------------------------------------------------------------------------
// MFMA f16 GEMM per batch b:  Y[o,j] = sum_k W[o,k] X[k,j]
//   GEMM1 (K=512): X rows 0..255 = x16, rows 256..511 = uf16 (both f16)
//   GEMM2 (K=256, G2): X = relu(sc[k]*y1[k,j]+sh[k]) folded at LDS-store time
// Block tile 128(o) x 256(j), BK=32, 4 waves (2x2), wave tile 64x128.
// Software-pipelined: prefetch K-step k+1 into regs during MFMA of step k.
// Xs rows permuted sigma(n)=(n&1)*128+(n>>1), 16B chunks XOR'd by (sigma&3)
//   -> staging writes and frag reads both at the b128 bank floor.
// grid (32, 2, 8), block 256.
// ---------------------------------------------------------------------------
template <int K, bool G2>
__global__ __launch_bounds__(256, 2) void mfma_gemm(
    const f16* __restrict__ Wf,
    const f16* __restrict__ Xh, const f16* __restrict__ Xh2,
    const float* __restrict__ sc, const float* __restrict__ sh,
    f16* __restrict__ Yh,
    float* __restrict__ psum, float* __restrict__ psq)
{
  __shared__ __align__(16) f16 Ws[128][40];   // [o][k], 80B rows
  __shared__ __align__(16) f16 Xs[256][40];   // [sigma][chunk^swz]
  const int t = threadIdx.x;
  const int l = t & 63, w = t >> 6;
  const int wm = w >> 1, wn = w & 1;
  const int g = l >> 4, ln = l & 15;
  const int jb = blockIdx.x * 256;
  const int ob = blockIdx.y * 128;
  const int b  = blockIdx.z;

  // W-stage mapping: it -> o = it*64 + (t>>2), kg = (t&3)*8
  const int wo0 = t >> 2, wkg = (t & 3) * 8;
  // X-stage mapping: adjacent column pair n0, n0+1; chunk cc = (t>>7) + it*2
  const int xn0 = (t & 127) * 2;
  const int xcc0 = t >> 7;
  const int s0 = t & 127, s1 = 128 + (t & 127);      // sigma rows
  const int xswz = t & 3;                             // sigma&3 (same for s0,s1)

  f32x4 acc[4][8];
#pragma unroll
  for (int i = 0; i < 4; ++i)
#pragma unroll
    for (int j = 0; j < 8; ++j) acc[i][j] = (f32x4){0.f, 0.f, 0.f, 0.f};

  f16x8 wr[2];
  f16x2 xr[2][8];

  // ---- prefetch into regs for K-step kb_ ----
  auto prefetch = [&](int kb_) {
#pragma unroll
    for (int it = 0; it < 2; ++it) {
      wr[it] = *(const f16x8*)&Wf[(size_t)(ob + it * 64 + wo0) * K + kb_ + wkg];
      const int kk = kb_ + (xcc0 + it * 2) * 8;
      const f16* src;
      if constexpr (!G2)
        src = (kk < C_) ? Xh + ((size_t)b * C_ + kk) * J_
                        : Xh2 + ((size_t)b * C_ + (kk - C_)) * J_;
      else
        src = Xh + ((size_t)b * C_ + kk) * J_;
      src += jb + xn0;
#pragma unroll
      for (int i = 0; i < 8; ++i) xr[it][i] = *(const f16x2*)&src[(size_t)i * J_];
    }
  };

  // ---- store prefetched regs into LDS (BN1-fold for G2 happens here) ----
  auto store_lds = [&](int kb_) {
#pragma unroll
    for (int it = 0; it < 2; ++it) {
      *(f16x8*)&Ws[it * 64 + wo0][wkg] = wr[it];
      const int cc = xcc0 + it * 2;
      const int col = (cc ^ xswz) * 8;
      f16x8 v0, v1;
      if constexpr (G2) {
        const int kk = kb_ + cc * 8;
#pragma unroll
        for (int i = 0; i < 8; ++i) {
          const float scv = sc[kk + i], shv = sh[kk + i];
          v0[i] = (f16)fmaxf((float)xr[it][i][0] * scv + shv, 0.f);
          v1[i] = (f16)fmaxf((float)xr[it][i][1] * scv + shv, 0.f);
        }
      } else {
#pragma unroll
        for (int i = 0; i < 8; ++i) { v0[i] = xr[it][i][0]; v1[i] = xr[it][i][1]; }
      }
      *(f16x8*)&Xs[s0][col] = v0;
      *(f16x8*)&Xs[s1][col] = v1;
    }
  };

  prefetch(0);
  for (int kb = 0; kb < K; kb += 32) {
    store_lds(kb);
    __syncthreads();
    if (kb + 32 < K) prefetch(kb + 32);   // in flight during MFMA phase

    f16x8 af[4], bf[8];
#pragma unroll
    for (int f = 0; f < 4; ++f)
      af[f] = *(const f16x8*)&Ws[wm * 64 + f * 16 + ln][g * 8];
#pragma unroll
    for (int f = 0; f < 8; ++f) {
      const int sg = (ln & 1) * 128 + wn * 64 + f * 8 + (ln >> 1);  // sigma(n)
      bf[f] = *(const f16x8*)&Xs[sg][(g ^ (sg & 3)) * 8];
    }
#pragma unroll
    for (int fm = 0; fm < 4; ++fm)
#pragma unroll
      for (int fn = 0; fn < 8; ++fn)
        acc[fm][fn] = __builtin_amdgcn_mfma_f32_16x16x32_f16(af[fm], bf[fn], acc[fm][fn], 0, 0, 0);
    __syncthreads();
  }

  // --- epilogue: f16 store + BN partials (slice2 = (b*32+jblk)*2+wn) ---
  const int slice2 = (b * 32 + blockIdx.x) * 2 + wn;
#pragma unroll
  for (int fm = 0; fm < 4; ++fm) {
#pragma unroll
    for (int r = 0; r < 4; ++r) {
      const int o = ob + wm * 64 + fm * 16 + g * 4 + r;   // D: row=(l>>4)*4+reg
      float s = 0.f, q = 0.f;
#pragma unroll
      for (int fn = 0; fn < 8; ++fn) {
        const float v = acc[fm][fn][r];
        const int j = jb + wn * 128 + fn * 16 + ln;        // D: col=lane&15
        Yh[((size_t)b * C_ + o) * J_ + j] = (f16)v;
        s += v; q += v * v;
      }
#pragma unroll
      for (int off = 1; off < 16; off <<= 1) {
        s += __shfl_xor(s, off);
        q += __shfl_xor(q, off);
      }
      if (ln == 0) {
        psum[(size_t)slice2 * C_ + o] = s;
        psq [(size_t)slice2 * C_ + o] = q;
      }
    }
  }
}

// ---------------------------------------------------------------------------
// BN finalize: one block per channel, sum NSLICE partials. grid 256
// ---------------------------------------------------------------------------
__global__ __launch_bounds__(256) void finalize_bn(
    const float* __restrict__ psum, const float* __restrict__ psq,
    const float* __restrict__ g, const float* __restrict__ bt,
    float* __restrict__ sc, float* __restrict__ sh)
{
  const int c = blockIdx.x, t = threadIdx.x;
  float s = 0.f, q = 0.f;
  for (int s2 = t; s2 < NSLICE; s2 += 256) {
    s += psum[(size_t)s2 * C_ + c];
    q += psq [(size_t)s2 * C_ + c];
  }
#pragma unroll
  for (int off = 1; off < 64; off <<= 1) {
    s += __shfl_xor(s, off);
    q += __shfl_xor(q, off);
  }
  __shared__ float ls[4], lq[4];
  if ((t & 63) == 0) { ls[t >> 6] = s; lq[t >> 6] = q; }
  __syncthreads();
  if (t == 0) {
    s = ls[0] + ls[1] + ls[2] + ls[3];
    q = lq[0] + lq[1] + lq[2] + lq[3];
    const float mean = s / BN_CNT;
    const float var = q / BN_CNT - mean * mean;
    const float rstd = rsqrtf(var + 1e-5f);
    const float scale = g[c] * rstd;
    sc[c] = scale;
    sh[c] = bt[c] - mean * scale;
  }
}

// ---------------------------------------------------------------------------
// BN2 + ReLU: f16 y2 (ws) -> fp32 d_out.  8 elems/thread. grid 8192, block 256
// ---------------------------------------------------------------------------
__global__ __launch_bounds__(256) void bn_relu_kernel(
    const f16* __restrict__ y2, float* __restrict__ out,
    const float* __restrict__ sc, const float* __restrict__ sh)
{
  const size_t i8 = (size_t)blockIdx.x * 256 + threadIdx.x;
  const int c = (int)((i8 >> 10) & (C_ - 1));   // 1024 8-elem units per (b,c)
  const float s = sc[c], h = sh[c];
  const f16x8 v = *(const f16x8*)&y2[i8 * 8];
  float4 o0, o1;
  o0.x = fmaxf((float)v[0] * s + h, 0.f);
  o0.y = fmaxf((float)v[1] * s + h, 0.f);
  o0.z = fmaxf((float)v[2] * s + h, 0.f);
  o0.w = fmaxf((float)v[3] * s + h, 0.f);
  o1.x = fmaxf((float)v[4] * s + h, 0.f);
  o1.y = fmaxf((float)v[5] * s + h, 0.f);
  o1.z = fmaxf((float)v[6] * s + h, 0.f);
  o1.w = fmaxf((float)v[7] * s + h, 0.f);
  ((float4*)out)[i8 * 2]     = o0;
  ((float4*)out)[i8 * 2 + 1] = o1;
}

// ---------------------------------------------------------------------------
extern "C" void kernel_launch(void* const* d_in, const int* in_sizes, int n_in,
                              void* d_out, int out_size, void* d_ws, size_t ws_size,
                              hipStream_t stream)
{
  const float* unknown = (const float*)d_in[0];
  const float* known   = (const float*)d_in[1];
  const float* uf      = (const float*)d_in[2];  // (B,256,4,N) fp32
  const float* kf      = (const float*)d_in[3];  // (B,256,4,M) fp32
  const float* W1      = (const float*)d_in[4];
  const float* g1      = (const float*)d_in[5];
  const float* b1      = (const float*)d_in[6];
  const float* W2      = (const float*)d_in[7];
  const float* g2      = (const float*)d_in[8];
  const float* b2      = (const float*)d_in[9];
  float* out = (float*)d_out;

  // ws layout (float-slot offsets); total ~36.4 MB
  float* wsf = (float*)d_ws;
  int*   idx   = (int*)d_ws;                 // 49152 ints
  float* wgt   = wsf + 49152;                // 49152
  float* sc1   = wsf + 98304;                // 256 each
  float* sh1   = wsf + 98560;
  float* sc2   = wsf + 98816;
  float* sh2   = wsf + 99072;
  float* p1s   = wsf + 99328;                // NSLICE*256 = 131072 each
  float* p1q   = wsf + 230400;
  float* p2s   = wsf + 361472;
  float* p2q   = wsf + 492544;
  f16*   w1h   = (f16*)(wsf + 623616);       // 131072 halves
  f16*   w2h   = (f16*)(wsf + 689152);       // 65536 halves
  f16*   x16   = (f16*)(wsf + 721920);       // interp16: 16,777,216 halves
  f16*   y2h   = x16;                        // y2 aliases x16 (dead after GEMM1)
  // d_out (67 MB) double duty: lower half = y1 (f16), upper half = uf16.
  // Both dead before bn_relu overwrites d_out with the final fp32 result.
  f16*   y1h   = (f16*)d_out;
  f16*   uf16  = (f16*)d_out + 16777216;

  cvt_w_kernel<<<512, 256, 0, stream>>>(W1, W2, w1h, w2h);
  knn_kernel<<<dim3(N_ / 32, B_), 256, 0, stream>>>(unknown, known, idx, wgt);
  // interp -> x16 AND uf -> uf16 in one heterogeneous launch
  prep_kernel<<<dim3(4, 96, 32), 256, 0, stream>>>(kf, idx, wgt, x16, uf, uf16);

  // GEMM1: y1 = W1 @ [x16 ; uf16]  (+ BN1 partials)
  mfma_gemm<CIN1, false><<<dim3(32, 2, 8), 256, 0, stream>>>(
      w1h, x16, uf16, nullptr, nullptr, y1h, p1s, p1q);
  finalize_bn<<<256, 256, 0, stream>>>(p1s, p1q, g1, b1, sc1, sh1);

  // GEMM2: y2 = W2 @ relu(bn1(y1)) -> f16 ws (+ BN2 partials)
  mfma_gemm<C_, true><<<dim3(32, 2, 8), 256, 0, stream>>>(
      w2h, y1h, nullptr, sc1, sh1, y2h, p2s, p2q);
  finalize_bn<<<256, 256, 0, stream>>>(p2s, p2q, g2, b2, sc2, sh2);

  // BN2 + ReLU: f16 (ws) -> fp32 out
  bn_relu_kernel<<<8192, 256, 0, stream>>>(y2h, out, sc2, sh2);
}

// Round 9
// 244.430 us; speedup vs baseline: 1.1186x; 1.1186x over previous
//
#include <hip/hip_runtime.h>
#include <math.h>

// Problem constants
#define B_   8
#define N_   2048
#define M_   512
#define C_   256
#define NR_  4
#define J_   8192          // NR_*N_ — contiguous column space per (b, channel)
#define CIN1 512
#define BN_CNT 65536.0f
#define NSLICE 512         // BN partial slices: 8 b * 32 jblk * 2 wn

using f16   = _Float16;
using f16x2 = __attribute__((ext_vector_type(2))) _Float16;
using f16x8 = __attribute__((ext_vector_type(8))) _Float16;
using f32x4 = __attribute__((ext_vector_type(4))) float;

// ---------------------------------------------------------------------------
// 3-NN + inverse-distance weights. 8 sub-lanes/point, shuffle-merge top-3.
// grid (N/32, B), block 256
// ---------------------------------------------------------------------------
#define KNN_INSERT(e, j)                                              \
  do {                                                                \
    if ((e) < d0)      { d2v = d1; i2 = i1; d1 = d0; i1 = i0; d0 = (e); i0 = (j); } \
    else if ((e) < d1) { d2v = d1; i2 = i1; d1 = (e); i1 = (j); }     \
    else if ((e) < d2v){ d2v = (e); i2 = (j); }                       \
  } while (0)

__global__ __launch_bounds__(256) void knn_kernel(
    const float* __restrict__ unknown, const float* __restrict__ known,
    int* __restrict__ idx_out, float* __restrict__ w_out)
{
  __shared__ float4 kp[M_];
  const int b = blockIdx.y;
  const int t = threadIdx.x;
  for (int i = t; i < M_; i += 256) {
    const float kx = known[(b * M_ + i) * 3 + 0];
    const float ky = known[(b * M_ + i) * 3 + 1];
    const float kz = known[(b * M_ + i) * 3 + 2];
    kp[(i & 63) * 8 + (i >> 6)] = make_float4(kx, ky, kz, kx * kx + ky * ky + kz * kz);
  }
  __syncthreads();

  const int p = t >> 3;          // point within block (0..31)
  const int s = t & 7;           // M-chunk (0..7)
  const int n = blockIdx.x * 32 + p;
  const float ux = unknown[(b * N_ + n) * 3 + 0];
  const float uy = unknown[(b * N_ + n) * 3 + 1];
  const float uz = unknown[(b * N_ + n) * 3 + 2];
  const float un2 = ux * ux + uy * uy + uz * uz;

  float d0 = 3.4e38f, d1 = 3.4e38f, d2v = 3.4e38f;
  int i0 = 0, i1 = 0, i2 = 0;
#pragma unroll 8
  for (int it = 0; it < 64; ++it) {
    const float4 k4 = kp[it * 8 + s];
    const int m = s * 64 + it;
    const float d = (un2 + k4.w) - 2.0f * (ux * k4.x + uy * k4.y + uz * k4.z);
    KNN_INSERT(d, m);
  }
#pragma unroll
  for (int off = 1; off < 8; off <<= 1) {
    const float e0 = __shfl_xor(d0, off), e1 = __shfl_xor(d1, off), e2 = __shfl_xor(d2v, off);
    const int   j0 = __shfl_xor(i0, off), j1 = __shfl_xor(i1, off), j2 = __shfl_xor(i2, off);
    KNN_INSERT(e0, j0);
    KNN_INSERT(e1, j1);
    KNN_INSERT(e2, j2);
  }
  if (s == 0) {
    const float r0 = 1.0f / (sqrtf(fmaxf(d0, 0.f)) + 1e-8f);
    const float r1 = 1.0f / (sqrtf(fmaxf(d1, 0.f)) + 1e-8f);
    const float r2 = 1.0f / (sqrtf(fmaxf(d2v, 0.f)) + 1e-8f);
    const float rs = r0 + r1 + r2;
    const int base = (b * N_ + n) * 3;
    idx_out[base + 0] = i0; idx_out[base + 1] = i1; idx_out[base + 2] = i2;
    w_out[base + 0] = r0 / rs; w_out[base + 1] = r1 / rs; w_out[base + 2] = r2 / rs;
  }
}

// ---------------------------------------------------------------------------
// interp: LDS-staged gather. Block loads its 4 kf rows (8KB) coalesced into
// LDS, then gathers from LDS (random ~2-way conflicts = near-free).
// 2 n's x 4 c's per thread.  grid (4, 64, 32), block 256
// ---------------------------------------------------------------------------
__global__ __launch_bounds__(256) void interp_kernel(
    const float* __restrict__ kf, const int* __restrict__ idx,
    const float* __restrict__ wgt, f16* __restrict__ out)
{
  __shared__ float rows[4][M_];   // 8 KB
  const int t = threadIdx.x;
  const int c0 = blockIdx.y * 4;
  const int b = blockIdx.z >> 2, r = blockIdx.z & 3;
#pragma unroll
  for (int cc = 0; cc < 4; ++cc) {
    const float* src = kf + (((size_t)b * C_ + c0 + cc) * NR_ + r) * M_;
#pragma unroll
    for (int u = 0; u < 2; ++u) rows[cc][u * 256 + t] = src[u * 256 + t];
  }
  __syncthreads();

  const int n0 = (blockIdx.x * 256 + t) * 2;
  const int ba = (b * N_ + n0) * 3;
  const int ia0 = idx[ba + 0], ia1 = idx[ba + 1], ia2 = idx[ba + 2];
  const int ib0 = idx[ba + 3], ib1 = idx[ba + 4], ib2 = idx[ba + 5];
  const float wa0 = wgt[ba + 0], wa1 = wgt[ba + 1], wa2 = wgt[ba + 2];
  const float wb0 = wgt[ba + 3], wb1 = wgt[ba + 4], wb2 = wgt[ba + 5];
#pragma unroll
  for (int cc = 0; cc < 4; ++cc) {
    f16x2 v;
    v[0] = (f16)(wa0 * rows[cc][ia0] + wa1 * rows[cc][ia1] + wa2 * rows[cc][ia2]);
    v[1] = (f16)(wb0 * rows[cc][ib0] + wb1 * rows[cc][ib1] + wb2 * rows[cc][ib2]);
    *(f16x2*)&out[(((size_t)b * C_ + c0 + cc) * NR_ + r) * N_ + n0] = v;
  }
}

// ---------------------------------------------------------------------------
// Weight fp32 -> f16 (W1 256x512, W2 256x256). grid 512, block 256
// ---------------------------------------------------------------------------
__global__ __launch_bounds__(256) void cvt_w_kernel(
    const float* __restrict__ W1, const float* __restrict__ W2,
    f16* __restrict__ w1h, f16* __restrict__ w2h)
{
  const int i = blockIdx.x * 256 + threadIdx.x;
  if (i < 256 * 512) w1h[i] = (f16)W1[i];
  if (i < 256 * 256) w2h[i] = (f16)W2[i];
}

// ---------------------------------------------------------------------------
// MFMA f16 GEMM per batch b:  Y[o,j] = sum_k W[o,k] X[k,j]
//   GEMM1 (K=512): X rows 0..255 = x16 (f16); rows 256..511 = uf (fp32, raw
//     bits prefetched, converted at LDS-store). K-steps are uniformly one
//     source type (split at kb==256), so no mixed step.
//   GEMM2 (K=256, G2): X = relu(sc[k]*y1[k,j]+sh[k]) folded at LDS-store.
// Block tile 128(o) x 256(j), BK=32, 4 waves (2x2), wave tile 64x128.
// Software-pipelined: prefetch K-step k+1 into regs during MFMA of step k.
// Xs rows permuted sigma(n)=(n&1)*128+(n>>1), 16B chunks XOR'd by (sigma&3).
// grid (32, 2, 8), block 256.
// ---------------------------------------------------------------------------
template <int K, bool G2>
__global__ __launch_bounds__(256, 2) void mfma_gemm(
    const f16* __restrict__ Wf,
    const f16* __restrict__ Xh, const float* __restrict__ Xf,
    const float* __restrict__ sc, const float* __restrict__ sh,
    f16* __restrict__ Yh,
    float* __restrict__ psum, float* __restrict__ psq)
{
  __shared__ __align__(16) f16 Ws[128][40];   // [o][k], 80B rows
  __shared__ __align__(16) f16 Xs[256][40];   // [sigma][chunk^swz]
  const int t = threadIdx.x;
  const int l = t & 63, w = t >> 6;
  const int wm = w >> 1, wn = w & 1;
  const int g = l >> 4, ln = l & 15;
  const int jb = blockIdx.x * 256;
  const int ob = blockIdx.y * 128;
  const int b  = blockIdx.z;

  // W-stage mapping: it -> o = it*64 + (t>>2), kg = (t&3)*8
  const int wo0 = t >> 2, wkg = (t & 3) * 8;
  // X-stage mapping: adjacent column pair n0, n0+1; chunk cc = (t>>7) + it*2
  const int xn0 = (t & 127) * 2;
  const int xcc0 = t >> 7;
  const int s0 = t & 127, s1 = 128 + (t & 127);      // sigma rows
  const int xswz = t & 3;                             // sigma&3 (same for s0,s1)

  f32x4 acc[4][8];
#pragma unroll
  for (int i = 0; i < 4; ++i)
#pragma unroll
    for (int j = 0; j < 8; ++j) acc[i][j] = (f32x4){0.f, 0.f, 0.f, 0.f};

  f16x8 wr[2];
  uint2 xr[2][8];   // raw bits: .x = f16x2 (f16 source) | .xy = float2 (fp32)

  // ---- prefetch raw bits for K-step kb_ (no cvt here: keeps waitcnt out
  //      of the MFMA phase) ----
  auto prefetch = [&](int kb_) {
#pragma unroll
    for (int it = 0; it < 2; ++it) {
      wr[it] = *(const f16x8*)&Wf[(size_t)(ob + it * 64 + wo0) * K + kb_ + wkg];
      const int kk = kb_ + (xcc0 + it * 2) * 8;
      if constexpr (!G2) {
        if (kk < C_) {
          const f16* src = Xh + ((size_t)b * C_ + kk) * J_ + jb + xn0;
#pragma unroll
          for (int i = 0; i < 8; ++i) xr[it][i].x = *(const unsigned int*)&src[(size_t)i * J_];
        } else {
          const float* src = Xf + ((size_t)b * C_ + (kk - C_)) * J_ + jb + xn0;
#pragma unroll
          for (int i = 0; i < 8; ++i) xr[it][i] = *(const uint2*)&src[(size_t)i * J_];
        }
      } else {
        const f16* src = Xh + ((size_t)b * C_ + kk) * J_ + jb + xn0;
#pragma unroll
        for (int i = 0; i < 8; ++i) xr[it][i].x = *(const unsigned int*)&src[(size_t)i * J_];
      }
    }
  };

  // ---- store prefetched regs into LDS (cvt + BN1-fold happen here) ----
  auto store_lds = [&](int kb_) {
#pragma unroll
    for (int it = 0; it < 2; ++it) {
      *(f16x8*)&Ws[it * 64 + wo0][wkg] = wr[it];
      const int cc = xcc0 + it * 2;
      const int col = (cc ^ xswz) * 8;
      f16x8 v0, v1;
      if constexpr (G2) {
        const int kk = kb_ + cc * 8;
#pragma unroll
        for (int i = 0; i < 8; ++i) {
          const f16x2 pr = __builtin_bit_cast(f16x2, xr[it][i].x);
          const float scv = sc[kk + i], shv = sh[kk + i];
          v0[i] = (f16)fmaxf((float)pr[0] * scv + shv, 0.f);
          v1[i] = (f16)fmaxf((float)pr[1] * scv + shv, 0.f);
        }
      } else if (kb_ < C_) {   // uniform per K-step: f16 source
#pragma unroll
        for (int i = 0; i < 8; ++i) {
          const f16x2 pr = __builtin_bit_cast(f16x2, xr[it][i].x);
          v0[i] = pr[0]; v1[i] = pr[1];
        }
      } else {                 // fp32 source
#pragma unroll
        for (int i = 0; i < 8; ++i) {
          const float2 pr = __builtin_bit_cast(float2, xr[it][i]);
          v0[i] = (f16)pr.x; v1[i] = (f16)pr.y;
        }
      }
      *(f16x8*)&Xs[s0][col] = v0;
      *(f16x8*)&Xs[s1][col] = v1;
    }
  };

  prefetch(0);
  for (int kb = 0; kb < K; kb += 32) {
    store_lds(kb);
    __syncthreads();
    if (kb + 32 < K) prefetch(kb + 32);   // in flight during MFMA phase

    f16x8 af[4], bf[8];
#pragma unroll
    for (int f = 0; f < 4; ++f)
      af[f] = *(const f16x8*)&Ws[wm * 64 + f * 16 + ln][g * 8];
#pragma unroll
    for (int f = 0; f < 8; ++f) {
      const int sg = (ln & 1) * 128 + wn * 64 + f * 8 + (ln >> 1);  // sigma(n)
      bf[f] = *(const f16x8*)&Xs[sg][(g ^ (sg & 3)) * 8];
    }
#pragma unroll
    for (int fm = 0; fm < 4; ++fm)
#pragma unroll
      for (int fn = 0; fn < 8; ++fn)
        acc[fm][fn] = __builtin_amdgcn_mfma_f32_16x16x32_f16(af[fm], bf[fn], acc[fm][fn], 0, 0, 0);
    __syncthreads();
  }

  // --- epilogue: f16 store + BN partials (slice2 = (b*32+jblk)*2+wn) ---
  const int slice2 = (b * 32 + blockIdx.x) * 2 + wn;
#pragma unroll
  for (int fm = 0; fm < 4; ++fm) {
#pragma unroll
    for (int r = 0; r < 4; ++r) {
      const int o = ob + wm * 64 + fm * 16 + g * 4 + r;   // D: row=(l>>4)*4+reg
      float s = 0.f, q = 0.f;
#pragma unroll
      for (int fn = 0; fn < 8; ++fn) {
        const float v = acc[fm][fn][r];
        const int j = jb + wn * 128 + fn * 16 + ln;        // D: col=lane&15
        Yh[((size_t)b * C_ + o) * J_ + j] = (f16)v;
        s += v; q += v * v;
      }
#pragma unroll
      for (int off = 1; off < 16; off <<= 1) {
        s += __shfl_xor(s, off);
        q += __shfl_xor(q, off);
      }
      if (ln == 0) {
        psum[(size_t)slice2 * C_ + o] = s;
        psq [(size_t)slice2 * C_ + o] = q;
      }
    }
  }
}

// ---------------------------------------------------------------------------
// BN finalize: one block per channel, sum NSLICE partials. grid 256
// ---------------------------------------------------------------------------
__global__ __launch_bounds__(256) void finalize_bn(
    const float* __restrict__ psum, const float* __restrict__ psq,
    const float* __restrict__ g, const float* __restrict__ bt,
    float* __restrict__ sc, float* __restrict__ sh)
{
  const int c = blockIdx.x, t = threadIdx.x;
  float s = 0.f, q = 0.f;
  for (int s2 = t; s2 < NSLICE; s2 += 256) {
    s += psum[(size_t)s2 * C_ + c];
    q += psq [(size_t)s2 * C_ + c];
  }
#pragma unroll
  for (int off = 1; off < 64; off <<= 1) {
    s += __shfl_xor(s, off);
    q += __shfl_xor(q, off);
  }
  __shared__ float ls[4], lq[4];
  if ((t & 63) == 0) { ls[t >> 6] = s; lq[t >> 6] = q; }
  __syncthreads();
  if (t == 0) {
    s = ls[0] + ls[1] + ls[2] + ls[3];
    q = lq[0] + lq[1] + lq[2] + lq[3];
    const float mean = s / BN_CNT;
    const float var = q / BN_CNT - mean * mean;
    const float rstd = rsqrtf(var + 1e-5f);
    const float scale = g[c] * rstd;
    sc[c] = scale;
    sh[c] = bt[c] - mean * scale;
  }
}

// ---------------------------------------------------------------------------
// BN2 + ReLU: f16 y2 (ws) -> fp32 d_out.  8 elems/thread. grid 8192, block 256
// ---------------------------------------------------------------------------
__global__ __launch_bounds__(256) void bn_relu_kernel(
    const f16* __restrict__ y2, float* __restrict__ out,
    const float* __restrict__ sc, const float* __restrict__ sh)
{
  const size_t i8 = (size_t)blockIdx.x * 256 + threadIdx.x;
  const int c = (int)((i8 >> 10) & (C_ - 1));   // 1024 8-elem units per (b,c)
  const float s = sc[c], h = sh[c];
  const f16x8 v = *(const f16x8*)&y2[i8 * 8];
  float4 o0, o1;
  o0.x = fmaxf((float)v[0] * s + h, 0.f);
  o0.y = fmaxf((float)v[1] * s + h, 0.f);
  o0.z = fmaxf((float)v[2] * s + h, 0.f);
  o0.w = fmaxf((float)v[3] * s + h, 0.f);
  o1.x = fmaxf((float)v[4] * s + h, 0.f);
  o1.y = fmaxf((float)v[5] * s + h, 0.f);
  o1.z = fmaxf((float)v[6] * s + h, 0.f);
  o1.w = fmaxf((float)v[7] * s + h, 0.f);
  ((float4*)out)[i8 * 2]     = o0;
  ((float4*)out)[i8 * 2 + 1] = o1;
}

// ---------------------------------------------------------------------------
extern "C" void kernel_launch(void* const* d_in, const int* in_sizes, int n_in,
                              void* d_out, int out_size, void* d_ws, size_t ws_size,
                              hipStream_t stream)
{
  const float* unknown = (const float*)d_in[0];
  const float* known   = (const float*)d_in[1];
  const float* uf      = (const float*)d_in[2];  // (B,256,4,N) fp32
  const float* kf      = (const float*)d_in[3];  // (B,256,4,M) fp32
  const float* W1      = (const float*)d_in[4];
  const float* g1      = (const float*)d_in[5];
  const float* b1      = (const float*)d_in[6];
  const float* W2      = (const float*)d_in[7];
  const float* g2      = (const float*)d_in[8];
  const float* b2      = (const float*)d_in[9];
  float* out = (float*)d_out;

  // ws layout (float-slot offsets); total ~36.4 MB
  float* wsf = (float*)d_ws;
  int*   idx   = (int*)d_ws;                 // 49152 ints
  float* wgt   = wsf + 49152;                // 49152
  float* sc1   = wsf + 98304;                // 256 each
  float* sh1   = wsf + 98560;
  float* sc2   = wsf + 98816;
  float* sh2   = wsf + 99072;
  float* p1s   = wsf + 99328;                // NSLICE*256 = 131072 each
  float* p1q   = wsf + 230400;
  float* p2s   = wsf + 361472;
  float* p2q   = wsf + 492544;
  f16*   w1h   = (f16*)(wsf + 623616);       // 131072 halves
  f16*   w2h   = (f16*)(wsf + 689152);       // 65536 halves
  f16*   x16   = (f16*)(wsf + 721920);       // interp16: 16,777,216 halves
  f16*   y2h   = x16;                        // y2 aliases x16 (dead after GEMM1)
  f16*   y1h   = (f16*)d_out;                // y1 parked in d_out (33.5 of 64 MB);
                                             // dead before bn_relu overwrites d_out

  cvt_w_kernel<<<512, 256, 0, stream>>>(W1, W2, w1h, w2h);
  knn_kernel<<<dim3(N_ / 32, B_), 256, 0, stream>>>(unknown, known, idx, wgt);
  interp_kernel<<<dim3(4, 64, 32), 256, 0, stream>>>(kf, idx, wgt, x16);

  // GEMM1: y1 = W1 @ [x16 ; uf(fp32)]  (+ BN1 partials)
  mfma_gemm<CIN1, false><<<dim3(32, 2, 8), 256, 0, stream>>>(
      w1h, x16, uf, nullptr, nullptr, y1h, p1s, p1q);
  finalize_bn<<<256, 256, 0, stream>>>(p1s, p1q, g1, b1, sc1, sh1);

  // GEMM2: y2 = W2 @ relu(bn1(y1)) -> f16 ws (+ BN2 partials)
  mfma_gemm<C_, true><<<dim3(32, 2, 8), 256, 0, stream>>>(
      w2h, y1h, nullptr, sc1, sh1, y2h, p2s, p2q);
  finalize_bn<<<256, 256, 0, stream>>>(p2s, p2q, g2, b2, sc2, sh2);

  // BN2 + ReLU: f16 (ws) -> fp32 out
  bn_relu_kernel<<<8192, 256, 0, stream>>>(y2h, out, sc2, sh2);
}